// Round 5
// baseline (13333.710 us; speedup 1.0000x reference)
//
#include <hip/hip_runtime.h>

#define L_SEQ 4096
#define I_DIM 512
#define H_DIM 2048
#define O_DIM 512
#define NBLK  128        // 128 participants, 1 unit/wave (serial chain unchanged)
#define UPB   16         // units per block -> one FULL private 64B LLC line
#define NTHR  1024
#define BUFS  4          // >=3 keeps tag-flow reuse skew-safe without barriers
#define RSTR (BUFS * H_DIM)   // u32 stride between mailbox replicas (32 KB)

// ws layout: [0:4K) logits u64[512] | [4K:4K+64) idx | [8K:...) replicas R x 32KB

typedef _Float16 h2 __attribute__((ext_vector_type(2)));
typedef float    f4 __attribute__((ext_vector_type(4)));
typedef unsigned int       u32;
typedef unsigned long long u64;

struct __attribute__((aligned(16))) H4 { h2 v[4]; };

#define ALOAD64(p)     __hip_atomic_load((p), __ATOMIC_RELAXED, __HIP_MEMORY_SCOPE_AGENT)
#define ASTORE64(p, v) __hip_atomic_store((p), (v), __ATOMIC_RELAXED, __HIP_MEMORY_SCOPE_AGENT)
#define ALOAD32(p)     __hip_atomic_load((p), __ATOMIC_RELAXED, __HIP_MEMORY_SCOPE_AGENT)
#define ASTORE32(p, v) __hip_atomic_store((p), (v), __ATOMIC_RELAXED, __HIP_MEMORY_SCOPE_AGENT)

// Dual-generation pipelined tagged poll of one 16B granule (4 tagged dwords).
// ENTIRE spin loop lives in one asm block: loads, checks, reissues, and the
// final vmcnt(0) drain — no in-flight-register hazards. Detection quantum
// ~ RT/2. Wave proceeds when ALL lanes' granules carry `tag`.
__device__ __forceinline__ void poll_granule(const u32* p, u32 tag,
                                             u32& r0, u32& r1, u32& r2, u32& r3) {
  u32 a0,a1,a2,a3,b0,b1,b2,b3,t0,t1,t2,t3;
  asm volatile(
    "global_load_dword %[a0], %[ptr], off sc0 sc1\n\t"
    "global_load_dword %[a1], %[ptr], off offset:4 sc0 sc1\n\t"
    "global_load_dword %[a2], %[ptr], off offset:8 sc0 sc1\n\t"
    "global_load_dword %[a3], %[ptr], off offset:12 sc0 sc1\n\t"
    "global_load_dword %[b0], %[ptr], off sc0 sc1\n\t"
    "global_load_dword %[b1], %[ptr], off offset:4 sc0 sc1\n\t"
    "global_load_dword %[b2], %[ptr], off offset:8 sc0 sc1\n\t"
    "global_load_dword %[b3], %[ptr], off offset:12 sc0 sc1\n\t"
    "Lpoll_%=:\n\t"
    "s_waitcnt vmcnt(4)\n\t"                  // generation A landed (B in flight)
    "v_lshrrev_b32 %[t0], 16, %[a0]\n\t"
    "v_lshrrev_b32 %[t1], 16, %[a1]\n\t"
    "v_lshrrev_b32 %[t2], 16, %[a2]\n\t"
    "v_lshrrev_b32 %[t3], 16, %[a3]\n\t"
    "v_xor_b32 %[t0], %[tg], %[t0]\n\t"
    "v_xor_b32 %[t1], %[tg], %[t1]\n\t"
    "v_xor_b32 %[t2], %[tg], %[t2]\n\t"
    "v_xor_b32 %[t3], %[tg], %[t3]\n\t"
    "v_or_b32 %[t0], %[t0], %[t1]\n\t"
    "v_or_b32 %[t2], %[t2], %[t3]\n\t"
    "v_or_b32 %[t0], %[t0], %[t2]\n\t"
    "v_cmp_ne_u32 vcc, 0, %[t0]\n\t"
    "s_nop 4\n\t"                             // VCC->vccz hazard guard
    "s_cbranch_vccz LgoodA_%=\n\t"
    "global_load_dword %[a0], %[ptr], off sc0 sc1\n\t"
    "global_load_dword %[a1], %[ptr], off offset:4 sc0 sc1\n\t"
    "global_load_dword %[a2], %[ptr], off offset:8 sc0 sc1\n\t"
    "global_load_dword %[a3], %[ptr], off offset:12 sc0 sc1\n\t"
    "s_waitcnt vmcnt(4)\n\t"                  // generation B landed (A in flight)
    "v_lshrrev_b32 %[t0], 16, %[b0]\n\t"
    "v_lshrrev_b32 %[t1], 16, %[b1]\n\t"
    "v_lshrrev_b32 %[t2], 16, %[b2]\n\t"
    "v_lshrrev_b32 %[t3], 16, %[b3]\n\t"
    "v_xor_b32 %[t0], %[tg], %[t0]\n\t"
    "v_xor_b32 %[t1], %[tg], %[t1]\n\t"
    "v_xor_b32 %[t2], %[tg], %[t2]\n\t"
    "v_xor_b32 %[t3], %[tg], %[t3]\n\t"
    "v_or_b32 %[t0], %[t0], %[t1]\n\t"
    "v_or_b32 %[t2], %[t2], %[t3]\n\t"
    "v_or_b32 %[t0], %[t0], %[t2]\n\t"
    "v_cmp_ne_u32 vcc, 0, %[t0]\n\t"
    "s_nop 4\n\t"
    "s_cbranch_vccz LgoodB_%=\n\t"
    "global_load_dword %[b0], %[ptr], off sc0 sc1\n\t"
    "global_load_dword %[b1], %[ptr], off offset:4 sc0 sc1\n\t"
    "global_load_dword %[b2], %[ptr], off offset:8 sc0 sc1\n\t"
    "global_load_dword %[b3], %[ptr], off offset:12 sc0 sc1\n\t"
    "s_sleep 1\n\t"                           // backoff per A+B cycle
    "s_branch Lpoll_%=\n\t"
    "LgoodB_%=:\n\t"
    "v_mov_b32 %[a0], %[b0]\n\t"
    "v_mov_b32 %[a1], %[b1]\n\t"
    "v_mov_b32 %[a2], %[b2]\n\t"
    "v_mov_b32 %[a3], %[b3]\n\t"
    "LgoodA_%=:\n\t"
    "s_waitcnt vmcnt(0)"                      // drain strays before regs escape
    : [a0]"=&v"(a0), [a1]"=&v"(a1), [a2]"=&v"(a2), [a3]"=&v"(a3),
      [b0]"=&v"(b0), [b1]"=&v"(b1), [b2]"=&v"(b2), [b3]"=&v"(b3),
      [t0]"=&v"(t0), [t1]"=&v"(t1), [t2]"=&v"(t2), [t3]"=&v"(t3)
    : [ptr]"v"(p), [tg]"s"(tag)
    : "vcc", "memory");
  r0 = a0; r1 = a1; r2 = a2; r3 = a3;
}

__device__ __forceinline__ float fdot2_(h2 a, h2 b, float c) {
#if __has_builtin(__builtin_amdgcn_fdot2)
  return __builtin_amdgcn_fdot2(a, b, c, false);
#else
  return c + (float)a[0] * (float)b[0] + (float)a[1] * (float)b[1];
#endif
}
__device__ __forceinline__ float fast_sigmoid(float x) {
  return __builtin_amdgcn_rcpf(1.f + __expf(-x));
}
__device__ __forceinline__ float fast_tanh(float x) {
  float xc = fminf(fmaxf(x, -15.f), 15.f);
  float e2 = __expf(2.f * xc);
  return (e2 - 1.f) * __builtin_amdgcn_rcpf(e2 + 1.f);
}

__device__ __forceinline__ u32 packh(u32 tag, float v) {
  union { _Float16 h; unsigned short u; } c; c.h = (_Float16)v;
  return (tag << 16) | (u32)c.u;
}
__device__ __forceinline__ float f16bits_to_f32(u32 w) {
  union { unsigned short u; _Float16 h; } c; c.u = (unsigned short)(w & 0xffff);
  return (float)c.h;
}
__device__ __forceinline__ u64 pack64(u32 tag, float v) {
  union { float f; u32 u; } c; c.f = v;
  return ((u64)tag << 32) | c.u;
}
__device__ __forceinline__ float val64(u64 pk) {
  union { u32 u; float f; } c; c.u = (u32)pk; return c.f;
}
__device__ __forceinline__ u32 tag64(u64 pk) { return (u32)(pk >> 32); }

struct WRegs {
  h2 w[3][5][4];     // [gate r/z/n][k-seg 0..4][pair]  seg0 = W_ih, seg1..4 = W_hh
  float bi[3], bh[3];
};

__device__ __forceinline__ void load_weights(WRegs& W, int j, int lane,
    const float* __restrict__ w_ih, const float* __restrict__ w_hh,
    const float* __restrict__ b_ih, const float* __restrict__ b_hh) {
#pragma unroll
  for (int g = 0; g < 3; ++g) {
    const float* rih = w_ih + ((size_t)g * H_DIM + j) * I_DIM + lane * 8;
#pragma unroll
    for (int hh = 0; hh < 2; ++hh) {
      f4 a = *(const f4*)(rih + 4 * hh);
      W.w[g][0][2*hh+0] = h2{(_Float16)a[0], (_Float16)a[1]};
      W.w[g][0][2*hh+1] = h2{(_Float16)a[2], (_Float16)a[3]};
    }
    const float* rhh = w_hh + ((size_t)g * H_DIM + j) * H_DIM + lane * 8;
#pragma unroll
    for (int s = 1; s < 5; ++s) {
#pragma unroll
      for (int hh = 0; hh < 2; ++hh) {
        f4 a = *(const f4*)(rhh + (s - 1) * 512 + 4 * hh);
        W.w[g][s][2*hh+0] = h2{(_Float16)a[0], (_Float16)a[1]};
        W.w[g][s][2*hh+1] = h2{(_Float16)a[2], (_Float16)a[3]};
      }
    }
    W.bi[g] = b_ih[g * H_DIM + j];
    W.bh[g] = b_hh[g * H_DIM + j];
  }
}

// Tag-synchronized h staging: poll own 16B granule, drop f16 payloads to LDS.
// Only tid<512 stage (512 x 16B = 8KB slot); waves 8..15 wait at the barrier.
__device__ __forceinline__ void stage4(_Float16* lbuf, const u32* p, u32 tag, int tid) {
  u32 v0, v1, v2, v3;
  poll_granule(p, tag, v0, v1, v2, v3);
  u64 pk = (u64)((v0 & 0xffffu) | (v1 << 16))
         | ((u64)((v2 & 0xffffu) | (v3 << 16)) << 32);
  *(u64*)(lbuf + tid * 4) = pk;
}

__device__ __forceinline__ void dot_h(const WRegs& W, const _Float16* lbuf, int lane,
                                      float& ar, float& az, float& anh) {
#pragma unroll
  for (int s = 1; s < 5; ++s) {
    H4 hh = *(const H4*)(lbuf + (s - 1) * 512 + lane * 8);
#pragma unroll
    for (int q = 0; q < 4; ++q) {
      ar  = fdot2_(W.w[0][s][q], hh.v[q], ar);
      az  = fdot2_(W.w[1][s][q], hh.v[q], az);
      anh = fdot2_(W.w[2][s][q], hh.v[q], anh);
    }
  }
}

// Wave-64 sum with a short chain: 4 DPP VALU adds + one ds_swizzle (xor16)
// + 2 readlanes. Result is wave-uniform.
__device__ __forceinline__ float wave_sum(float v) {
  v += __int_as_float(__builtin_amdgcn_update_dpp(0, __float_as_int(v), 0xB1, 0xf, 0xf, false));  // quad_perm [1,0,3,2]
  v += __int_as_float(__builtin_amdgcn_update_dpp(0, __float_as_int(v), 0x4E, 0xf, 0xf, false));  // quad_perm [2,3,0,1]
  v += __int_as_float(__builtin_amdgcn_update_dpp(0, __float_as_int(v), 0x141, 0xf, 0xf, false)); // row_half_mirror
  v += __int_as_float(__builtin_amdgcn_update_dpp(0, __float_as_int(v), 0x140, 0xf, 0xf, false)); // row_mirror
  v += __int_as_float(__builtin_amdgcn_ds_swizzle(__float_as_int(v), 0x401F));                    // xor 16
  float a = __int_as_float(__builtin_amdgcn_readlane(__float_as_int(v), 0));
  float b = __int_as_float(__builtin_amdgcn_readlane(__float_as_int(v), 32));
  return a + b;
}

__global__ void __launch_bounds__(NTHR, 1) rnn_persistent(
    const float* __restrict__ input_,
    const float* __restrict__ ewih, const float* __restrict__ ewhh,
    const float* __restrict__ ebih, const float* __restrict__ ebhh,
    const float* __restrict__ dwih, const float* __restrict__ dwhh,
    const float* __restrict__ dbih, const float* __restrict__ dbhh,
    const float* __restrict__ h2ow, const float* __restrict__ h2ob,
    float* __restrict__ out, char* __restrict__ ws, int tdec, int R)
{
  __shared__ alignas(16) _Float16 h_lds[2 * H_DIM];   // double buffer (parity of t)
  __shared__ float hred[UPB];
  __shared__ float redm[16], reds[16];
  __shared__ int   sidx[16];
  __shared__ int   idx_sh;

  u64* logits = (u64*)ws;
  u64* idxp   = (u64*)(ws + 4096);
  u32* gex    = (u32*)(ws + 8192);                 // replica 0 base

  const int tid  = threadIdx.x;
  const int lane = tid & 63;
  const int wid  = tid >> 6;
  const int blk  = blockIdx.x;
  const int j    = blk * UPB + wid;                // hidden unit owned by this wave
  const u32* gexr = gex + (size_t)(blk & (R - 1)) * RSTR;  // replica this block polls

  WRegs W;
  load_weights(W, j, lane, ewih, ewhh, ebih, ebhh);
  float brz0 = W.bi[0] + W.bh[0];
  float brz1 = W.bi[1] + W.bh[1];

  float hold = 0.f;   // exact fp32 carry of h_j

  // ---------------- encoder ----------------
  // iter t: consume h(t) [tag t, slot t&3]; produce h(t+1) into ALL replicas
  // via wave 0: 16 units x 4B = one FULL PRIVATE 64B line per replica per
  // block — no cross-block false sharing at the LLC (vs 2x32B half-lines at
  // NBLK=256). Per-wave serial work identical to the 256-block variant.
  for (u32 t = 0; t < L_SEQ; ++t) {
    _Float16* lbuf = h_lds + (t & 1) * H_DIM;
    const float* xr = input_ + (size_t)t * I_DIM + lane * 8;
    f4 xa = *(const f4*)xr;                  // issue early; consume post-detect
    f4 xb = *(const f4*)(xr + 4);

    if (t) __builtin_amdgcn_s_sleep(32);   // ~2048cy backoff: poll-flood cut
    if (tid < 512)
      stage4(lbuf, gexr + (t & (BUFS - 1)) * H_DIM + tid * 4, t & 0xffffu, tid);

    // x-projection (post-detect; overlaps other waves' staging, pre-barrier)
    h2 xv[4] = { h2{(_Float16)xa[0], (_Float16)xa[1]}, h2{(_Float16)xa[2], (_Float16)xa[3]},
                 h2{(_Float16)xb[0], (_Float16)xb[1]}, h2{(_Float16)xb[2], (_Float16)xb[3]} };
    float ar = 0.f, az = 0.f, anx = 0.f, anh = 0.f;
#pragma unroll
    for (int q = 0; q < 4; ++q) {
      ar  = fdot2_(W.w[0][0][q], xv[q], ar);
      az  = fdot2_(W.w[1][0][q], xv[q], az);
      anx = fdot2_(W.w[2][0][q], xv[q], anx);
    }
    __syncthreads();   // stage4 LDS writes visible to all waves' dot_h reads

    dot_h(W, lbuf, lane, ar, az, anh);
    ar  = wave_sum(ar);
    az  = wave_sum(az);
    anx = wave_sum(anx);
    anh = wave_sum(anh);

    float r = fast_sigmoid(ar + brz0);
    float z = fast_sigmoid(az + brz1);
    float n = fast_tanh(anx + W.bi[2] + r * (anh + W.bh[2]));
    hold = (1.f - z) * n + z * hold;

    // coalesced multicast: lane 16k+i of wave 0 stores word i of replica k
    // (two passes cover up to 8 replicas), each store = one full 64B line
    if (lane == 0) hred[wid] = hold;
    __syncthreads();
    if (wid == 0) {
      const u32 tg = (t + 1) & 0xffffu;
      const u32 sl = (t + 1) & (BUFS - 1);
      const int rep = lane >> 4, wi = lane & 15;
      u32 pk = packh(tg, hred[wi]);
      u32* base = (u32*)gex + sl * H_DIM + blk * UPB + wi;
      if (rep < R)     ASTORE32(base + (size_t)rep * RSTR, pk);
      if (rep + 4 < R) ASTORE32(base + (size_t)(rep + 4) * RSTR, pk);
    }
  }

  // ---------------- decoder ----------------
  load_weights(W, j, lane, dwih, dwhh, dbih, dbhh);
  brz0 = W.bi[0] + W.bh[0];
  brz1 = W.bi[1] + W.bh[1];
  __syncthreads();

  for (int d = 0; d < tdec; ++d) {
    const u32 t = L_SEQ + (u32)d;
    _Float16* lbuf = h_lds + (t & 1) * H_DIM;

    if (tid == 0) {
      int ix = -1;
      if (d > 0) {                          // poll one-hot index {tag d}
        u64 pk = ALOAD64(idxp);
        while (tag64(pk) != (u32)d) { __builtin_amdgcn_s_sleep(1); pk = ALOAD64(idxp); }
        ix = (int)(u32)pk;
      }
      idx_sh = ix;
    }
    if (tid < 512)
      stage4(lbuf, gexr + (t & (BUFS - 1)) * H_DIM + tid * 4, t & 0xffffu, tid);
    __syncthreads();
    const int idx = idx_sh;

    float ar = 0.f, az = 0.f, anx = 0.f, anh = 0.f;
    if (idx >= 0 && lane == (idx >> 3)) {
      const int qq = (idx & 7) >> 1;
      const int pp = idx & 1;
#pragma unroll
      for (int q = 0; q < 4; ++q) if (q == qq) {
        ar  += pp ? (float)W.w[0][0][q][1] : (float)W.w[0][0][q][0];
        az  += pp ? (float)W.w[1][0][q][1] : (float)W.w[1][0][q][0];
        anx += pp ? (float)W.w[2][0][q][1] : (float)W.w[2][0][q][0];
      }
    }
    dot_h(W, lbuf, lane, ar, az, anh);
    ar  = wave_sum(ar);
    az  = wave_sum(az);
    anx = wave_sum(anx);
    anh = wave_sum(anh);

    float r = fast_sigmoid(ar + brz0);
    float z = fast_sigmoid(az + brz1);
    float n = fast_tanh(anx + W.bi[2] + r * (anh + W.bh[2]));
    hold = (1.f - z) * n + z * hold;

    if (lane == 0) hred[wid] = hold;
    __syncthreads();
    if (wid == 0) {
      const u32 tg = (t + 1) & 0xffffu;
      const u32 sl = (t + 1) & (BUFS - 1);
      const int rep = lane >> 4, wi = lane & 15;
      u32 pk = packh(tg, hred[wi]);
      u32* base = (u32*)gex + sl * H_DIM + blk * UPB + wi;
      if (rep < R)     ASTORE32(base + (size_t)rep * RSTR, pk);
      if (rep + 4 < R) ASTORE32(base + (size_t)(rep + 4) * RSTR, pk);
    }

    // ---- logits: rows 4*blk..4*blk+3; consume h(t+1) from own replica ----
    {
      const int rl  = tid >> 8;                  // row-local 0..3 (256 thr/row)
      const int row = 4 * blk + rl;
      const int kk  = (tid & 255) * 8;
      const float* wrow = h2ow + (size_t)row * H_DIM + kk;
      f4 wa = *(const f4*)wrow, wb = *(const f4*)(wrow + 4);
      const u32* hp = gexr + ((t + 1) & (BUFS - 1)) * H_DIM + kk;
      const u32 htag = (t + 1) & 0xffffu;
      u32 g0, g1, g2, g3, g4, g5, g6, g7;
      poll_granule(hp,     htag, g0, g1, g2, g3);
      poll_granule(hp + 4, htag, g4, g5, g6, g7);
      float s = wa[0]*f16bits_to_f32(g0) + wa[1]*f16bits_to_f32(g1)
              + wa[2]*f16bits_to_f32(g2) + wa[3]*f16bits_to_f32(g3)
              + wb[0]*f16bits_to_f32(g4) + wb[1]*f16bits_to_f32(g5)
              + wb[2]*f16bits_to_f32(g6) + wb[3]*f16bits_to_f32(g7);
      s = wave_sum(s);
      if (lane == 0) redm[wid] = s;
      __syncthreads();
      if ((tid & 255) == 0)                      // one thread per row
        ASTORE64(&logits[row],
                 pack64((u32)(d + 1),
                        redm[4 * rl] + redm[4 * rl + 1] + redm[4 * rl + 2] +
                        redm[4 * rl + 3] + h2ob[row]));
    }
    __syncthreads();

    // ---- log-softmax + argmax on block 0 (consumes tagged logits) ----
    // All 1024 threads run the section (uniform barriers); tid>=512 carries
    // -inf so it never wins max and adds 0 to the sum.
    if (blk == 0) {
      float v = -__builtin_inff();
      if (tid < 512) {
        u64 pk = ALOAD64(&logits[tid]);
        while (tag64(pk) != (u32)(d + 1)) { __builtin_amdgcn_s_sleep(1); pk = ALOAD64(&logits[tid]); }
        v = val64(pk);
      }
      float m = v; int mi = tid;
#pragma unroll
      for (int off = 32; off > 0; off >>= 1) {
        float om = __shfl_xor(m, off, 64);
        int   oi = __shfl_xor(mi, off, 64);
        if (om > m || (om == m && oi < mi)) { m = om; mi = oi; }
      }
      if (lane == 0) { redm[wid] = m; sidx[wid] = mi; }
      __syncthreads();
      float M = redm[0]; int MI = sidx[0];
#pragma unroll
      for (int w2 = 1; w2 < 8; ++w2)
        if (redm[w2] > M || (redm[w2] == M && sidx[w2] < MI)) { M = redm[w2]; MI = sidx[w2]; }
      float ss = (tid < 512) ? __expf(v - M) : 0.f;
#pragma unroll
      for (int off = 32; off > 0; off >>= 1) ss += __shfl_xor(ss, off, 64);
      if (lane == 0) reds[wid] = ss;
      __syncthreads();
      float S = reds[0] + reds[1] + reds[2] + reds[3]
              + reds[4] + reds[5] + reds[6] + reds[7];
      if (tid < 512)
        out[(size_t)d * O_DIM + tid] = v - M - __logf(S);
      if (tid == 0)
        ASTORE64(idxp, pack64((u32)(d + 1), (u32)MI));
    }
    __syncthreads();   // LDS reuse guard (decoder only; negligible at 30 steps)
  }
}

extern "C" void kernel_launch(void* const* d_in, const int* in_sizes, int n_in,
                              void* d_out, int out_size, void* d_ws, size_t ws_size,
                              hipStream_t stream) {
  const float* input_ = (const float*)d_in[0];
  const float* ewih   = (const float*)d_in[1];
  const float* ewhh   = (const float*)d_in[2];
  const float* ebih   = (const float*)d_in[3];
  const float* ebhh   = (const float*)d_in[4];
  const float* dwih   = (const float*)d_in[5];
  const float* dwhh   = (const float*)d_in[6];
  const float* dbih   = (const float*)d_in[7];
  const float* dbhh   = (const float*)d_in[8];
  const float* h2ow   = (const float*)d_in[9];
  const float* h2ob   = (const float*)d_in[10];
  float* out = (float*)d_out;
  char*  ws  = (char*)d_ws;
  int tdec = out_size / O_DIM;   // 30

  // replica count from actual workspace size (R=1 degrades gracefully)
  int R = 1;
  if (ws_size >= 8192 + 32768) {
    size_t maxr = (ws_size - 8192) / 32768;
    while (R * 2 <= (int)(maxr < 8 ? maxr : 8)) R *= 2;
  }
  size_t zbytes = 8192 + (size_t)R * 32768;

  // zero logits+idx+replicas (tag0 == valid h(0)=0 in every replica)
  hipMemsetAsync(d_ws, 0, zbytes, stream);

  void* args[] = { (void*)&input_, (void*)&ewih, (void*)&ewhh, (void*)&ebih, (void*)&ebhh,
                   (void*)&dwih, (void*)&dwhh, (void*)&dbih, (void*)&dbhh,
                   (void*)&h2ow, (void*)&h2ob, (void*)&out, (void*)&ws, (void*)&tdec,
                   (void*)&R };
  hipLaunchCooperativeKernel((void*)rnn_persistent, dim3(NBLK), dim3(NTHR),
                             args, 0, stream);
}

// Round 6
// 12875.394 us; speedup vs baseline: 1.0356x; 1.0356x over previous
//
#include <hip/hip_runtime.h>

#define L_SEQ 4096
#define I_DIM 512
#define H_DIM 2048
#define O_DIM 512
#define NBLK  256
#define NTHR  512
#define BUFS  4          // >=3 keeps tag-flow reuse skew-safe without barriers
#define RSTR (BUFS * H_DIM)   // u32 stride between mailbox replicas (32 KB)

// ws layout: [0:4K) logits u64[512] | [4K:4K+64) idx | [8K:...) replicas R x 32KB

typedef _Float16 h2 __attribute__((ext_vector_type(2)));
typedef float    f4 __attribute__((ext_vector_type(4)));
typedef unsigned int       u32;
typedef unsigned long long u64;

struct __attribute__((aligned(16))) H4 { h2 v[4]; };

#define ALOAD64(p)     __hip_atomic_load((p), __ATOMIC_RELAXED, __HIP_MEMORY_SCOPE_AGENT)
#define ASTORE64(p, v) __hip_atomic_store((p), (v), __ATOMIC_RELAXED, __HIP_MEMORY_SCOPE_AGENT)
#define ALOAD32(p)     __hip_atomic_load((p), __ATOMIC_RELAXED, __HIP_MEMORY_SCOPE_AGENT)
#define ASTORE32(p, v) __hip_atomic_store((p), (v), __ATOMIC_RELAXED, __HIP_MEMORY_SCOPE_AGENT)

// Single-shot tagged check of one 16B granule: 4 loads, full drain, verdict in
// SGPR (wave-uniform). The straggler block (whose entry gates the global step)
// exits here in ~1 RT with NO backoff sleep. Pre-issued x loads (L2-resident)
// drain under this check's own LLC RT — no added stall.
__device__ __forceinline__ int try_granule(const u32* p, u32 tag,
                                           u32& r0, u32& r1, u32& r2, u32& r3) {
  u32 a0,a1,a2,a3,t0,t1,t2,t3,bad;
  asm volatile(
    "global_load_dword %[a0], %[ptr], off sc0 sc1\n\t"
    "global_load_dword %[a1], %[ptr], off offset:4 sc0 sc1\n\t"
    "global_load_dword %[a2], %[ptr], off offset:8 sc0 sc1\n\t"
    "global_load_dword %[a3], %[ptr], off offset:12 sc0 sc1\n\t"
    "s_waitcnt vmcnt(0)\n\t"
    "v_lshrrev_b32 %[t0], 16, %[a0]\n\t"
    "v_lshrrev_b32 %[t1], 16, %[a1]\n\t"
    "v_lshrrev_b32 %[t2], 16, %[a2]\n\t"
    "v_lshrrev_b32 %[t3], 16, %[a3]\n\t"
    "v_xor_b32 %[t0], %[tg], %[t0]\n\t"
    "v_xor_b32 %[t1], %[tg], %[t1]\n\t"
    "v_xor_b32 %[t2], %[tg], %[t2]\n\t"
    "v_xor_b32 %[t3], %[tg], %[t3]\n\t"
    "v_or_b32 %[t0], %[t0], %[t1]\n\t"
    "v_or_b32 %[t2], %[t2], %[t3]\n\t"
    "v_or_b32 %[t0], %[t0], %[t2]\n\t"
    "v_cmp_ne_u32 vcc, 0, %[t0]\n\t"
    "s_nop 4\n\t"                             // VALU->SALU vcc read hazard guard
    "s_or_b32 %[bad], vcc_lo, vcc_hi\n\t"
    : [a0]"=&v"(a0), [a1]"=&v"(a1), [a2]"=&v"(a2), [a3]"=&v"(a3),
      [t0]"=&v"(t0), [t1]"=&v"(t1), [t2]"=&v"(t2), [t3]"=&v"(t3),
      [bad]"=s"(bad)
    : [ptr]"v"(p), [tg]"s"(tag)
    : "vcc", "memory");
  r0 = a0; r1 = a1; r2 = a2; r3 = a3;
  return bad == 0;
}

// Dual-generation pipelined tagged poll of one 16B granule (4 tagged dwords).
// ENTIRE spin loop lives in one asm block: loads, checks, reissues, and the
// final vmcnt(0) drain — no in-flight-register hazards. Detection quantum
// ~ RT/2. Wave proceeds when ALL lanes' granules carry `tag`.
__device__ __forceinline__ void poll_granule(const u32* p, u32 tag,
                                             u32& r0, u32& r1, u32& r2, u32& r3) {
  u32 a0,a1,a2,a3,b0,b1,b2,b3,t0,t1,t2,t3;
  asm volatile(
    "global_load_dword %[a0], %[ptr], off sc0 sc1\n\t"
    "global_load_dword %[a1], %[ptr], off offset:4 sc0 sc1\n\t"
    "global_load_dword %[a2], %[ptr], off offset:8 sc0 sc1\n\t"
    "global_load_dword %[a3], %[ptr], off offset:12 sc0 sc1\n\t"
    "global_load_dword %[b0], %[ptr], off sc0 sc1\n\t"
    "global_load_dword %[b1], %[ptr], off offset:4 sc0 sc1\n\t"
    "global_load_dword %[b2], %[ptr], off offset:8 sc0 sc1\n\t"
    "global_load_dword %[b3], %[ptr], off offset:12 sc0 sc1\n\t"
    "Lpoll_%=:\n\t"
    "s_waitcnt vmcnt(4)\n\t"                  // generation A landed (B in flight)
    "v_lshrrev_b32 %[t0], 16, %[a0]\n\t"
    "v_lshrrev_b32 %[t1], 16, %[a1]\n\t"
    "v_lshrrev_b32 %[t2], 16, %[a2]\n\t"
    "v_lshrrev_b32 %[t3], 16, %[a3]\n\t"
    "v_xor_b32 %[t0], %[tg], %[t0]\n\t"
    "v_xor_b32 %[t1], %[tg], %[t1]\n\t"
    "v_xor_b32 %[t2], %[tg], %[t2]\n\t"
    "v_xor_b32 %[t3], %[tg], %[t3]\n\t"
    "v_or_b32 %[t0], %[t0], %[t1]\n\t"
    "v_or_b32 %[t2], %[t2], %[t3]\n\t"
    "v_or_b32 %[t0], %[t0], %[t2]\n\t"
    "v_cmp_ne_u32 vcc, 0, %[t0]\n\t"
    "s_nop 4\n\t"                             // VCC->vccz hazard guard
    "s_cbranch_vccz LgoodA_%=\n\t"
    "global_load_dword %[a0], %[ptr], off sc0 sc1\n\t"
    "global_load_dword %[a1], %[ptr], off offset:4 sc0 sc1\n\t"
    "global_load_dword %[a2], %[ptr], off offset:8 sc0 sc1\n\t"
    "global_load_dword %[a3], %[ptr], off offset:12 sc0 sc1\n\t"
    "s_waitcnt vmcnt(4)\n\t"                  // generation B landed (A in flight)
    "v_lshrrev_b32 %[t0], 16, %[b0]\n\t"
    "v_lshrrev_b32 %[t1], 16, %[b1]\n\t"
    "v_lshrrev_b32 %[t2], 16, %[b2]\n\t"
    "v_lshrrev_b32 %[t3], 16, %[b3]\n\t"
    "v_xor_b32 %[t0], %[tg], %[t0]\n\t"
    "v_xor_b32 %[t1], %[tg], %[t1]\n\t"
    "v_xor_b32 %[t2], %[tg], %[t2]\n\t"
    "v_xor_b32 %[t3], %[tg], %[t3]\n\t"
    "v_or_b32 %[t0], %[t0], %[t1]\n\t"
    "v_or_b32 %[t2], %[t2], %[t3]\n\t"
    "v_or_b32 %[t0], %[t0], %[t2]\n\t"
    "v_cmp_ne_u32 vcc, 0, %[t0]\n\t"
    "s_nop 4\n\t"
    "s_cbranch_vccz LgoodB_%=\n\t"
    "global_load_dword %[b0], %[ptr], off sc0 sc1\n\t"
    "global_load_dword %[b1], %[ptr], off offset:4 sc0 sc1\n\t"
    "global_load_dword %[b2], %[ptr], off offset:8 sc0 sc1\n\t"
    "global_load_dword %[b3], %[ptr], off offset:12 sc0 sc1\n\t"
    "s_sleep 1\n\t"                           // backoff per A+B cycle
    "s_branch Lpoll_%=\n\t"
    "LgoodB_%=:\n\t"
    "v_mov_b32 %[a0], %[b0]\n\t"
    "v_mov_b32 %[a1], %[b1]\n\t"
    "v_mov_b32 %[a2], %[b2]\n\t"
    "v_mov_b32 %[a3], %[b3]\n\t"
    "LgoodA_%=:\n\t"
    "s_waitcnt vmcnt(0)"                      // drain strays before regs escape
    : [a0]"=&v"(a0), [a1]"=&v"(a1), [a2]"=&v"(a2), [a3]"=&v"(a3),
      [b0]"=&v"(b0), [b1]"=&v"(b1), [b2]"=&v"(b2), [b3]"=&v"(b3),
      [t0]"=&v"(t0), [t1]"=&v"(t1), [t2]"=&v"(t2), [t3]"=&v"(t3)
    : [ptr]"v"(p), [tg]"s"(tag)
    : "vcc", "memory");
  r0 = a0; r1 = a1; r2 = a2; r3 = a3;
}

// check-then-backoff: straggler exits in 1 RT; waiters sleep ~853ns then spin.
__device__ __forceinline__ void poll_bk(const u32* p, u32 tag,
                                        u32& r0, u32& r1, u32& r2, u32& r3) {
  if (try_granule(p, tag, r0, r1, r2, r3)) return;
  __builtin_amdgcn_s_sleep(32);
  poll_granule(p, tag, r0, r1, r2, r3);
}

__device__ __forceinline__ float fdot2_(h2 a, h2 b, float c) {
#if __has_builtin(__builtin_amdgcn_fdot2)
  return __builtin_amdgcn_fdot2(a, b, c, false);
#else
  return c + (float)a[0] * (float)b[0] + (float)a[1] * (float)b[1];
#endif
}
__device__ __forceinline__ float fast_sigmoid(float x) {
  return __builtin_amdgcn_rcpf(1.f + __expf(-x));
}
__device__ __forceinline__ float fast_tanh(float x) {
  float xc = fminf(fmaxf(x, -15.f), 15.f);
  float e2 = __expf(2.f * xc);
  return (e2 - 1.f) * __builtin_amdgcn_rcpf(e2 + 1.f);
}

__device__ __forceinline__ u32 packh(u32 tag, float v) {
  union { _Float16 h; unsigned short u; } c; c.h = (_Float16)v;
  return (tag << 16) | (u32)c.u;
}
__device__ __forceinline__ float f16bits_to_f32(u32 w) {
  union { unsigned short u; _Float16 h; } c; c.u = (unsigned short)(w & 0xffff);
  return (float)c.h;
}
__device__ __forceinline__ u64 pack64(u32 tag, float v) {
  union { float f; u32 u; } c; c.f = v;
  return ((u64)tag << 32) | c.u;
}
__device__ __forceinline__ float val64(u64 pk) {
  union { u32 u; float f; } c; c.u = (u32)pk; return c.f;
}
__device__ __forceinline__ u32 tag64(u64 pk) { return (u32)(pk >> 32); }

struct WRegs {
  h2 w[3][5][4];     // [gate r/z/n][k-seg 0..4][pair]  seg0 = W_ih, seg1..4 = W_hh
  float bi[3], bh[3];
};

__device__ __forceinline__ void load_weights(WRegs& W, int j, int lane,
    const float* __restrict__ w_ih, const float* __restrict__ w_hh,
    const float* __restrict__ b_ih, const float* __restrict__ b_hh) {
#pragma unroll
  for (int g = 0; g < 3; ++g) {
    const float* rih = w_ih + ((size_t)g * H_DIM + j) * I_DIM + lane * 8;
#pragma unroll
    for (int hh = 0; hh < 2; ++hh) {
      f4 a = *(const f4*)(rih + 4 * hh);
      W.w[g][0][2*hh+0] = h2{(_Float16)a[0], (_Float16)a[1]};
      W.w[g][0][2*hh+1] = h2{(_Float16)a[2], (_Float16)a[3]};
    }
    const float* rhh = w_hh + ((size_t)g * H_DIM + j) * H_DIM + lane * 8;
#pragma unroll
    for (int s = 1; s < 5; ++s) {
#pragma unroll
      for (int hh = 0; hh < 2; ++hh) {
        f4 a = *(const f4*)(rhh + (s - 1) * 512 + 4 * hh);
        W.w[g][s][2*hh+0] = h2{(_Float16)a[0], (_Float16)a[1]};
        W.w[g][s][2*hh+1] = h2{(_Float16)a[2], (_Float16)a[3]};
      }
    }
    W.bi[g] = b_ih[g * H_DIM + j];
    W.bh[g] = b_hh[g * H_DIM + j];
  }
}

// Tag-synchronized h staging: poll own 16B granule, drop f16 payloads to LDS.
__device__ __forceinline__ void stage4(_Float16* lbuf, const u32* p, u32 tag, int tid) {
  u32 v0, v1, v2, v3;
  poll_bk(p, tag, v0, v1, v2, v3);
  u64 pk = (u64)((v0 & 0xffffu) | (v1 << 16))
         | ((u64)((v2 & 0xffffu) | (v3 << 16)) << 32);
  *(u64*)(lbuf + tid * 4) = pk;
}

__device__ __forceinline__ void dot_h(const WRegs& W, const _Float16* lbuf, int lane,
                                      float& ar, float& az, float& anh) {
#pragma unroll
  for (int s = 1; s < 5; ++s) {
    H4 hh = *(const H4*)(lbuf + (s - 1) * 512 + lane * 8);
#pragma unroll
    for (int q = 0; q < 4; ++q) {
      ar  = fdot2_(W.w[0][s][q], hh.v[q], ar);
      az  = fdot2_(W.w[1][s][q], hh.v[q], az);
      anh = fdot2_(W.w[2][s][q], hh.v[q], anh);
    }
  }
}

// Wave-64 sum with a short chain: 4 DPP VALU adds + one ds_swizzle (xor16)
// + 2 readlanes. Result is wave-uniform.
__device__ __forceinline__ float wave_sum(float v) {
  v += __int_as_float(__builtin_amdgcn_update_dpp(0, __float_as_int(v), 0xB1, 0xf, 0xf, false));  // quad_perm [1,0,3,2]
  v += __int_as_float(__builtin_amdgcn_update_dpp(0, __float_as_int(v), 0x4E, 0xf, 0xf, false));  // quad_perm [2,3,0,1]
  v += __int_as_float(__builtin_amdgcn_update_dpp(0, __float_as_int(v), 0x141, 0xf, 0xf, false)); // row_half_mirror
  v += __int_as_float(__builtin_amdgcn_update_dpp(0, __float_as_int(v), 0x140, 0xf, 0xf, false)); // row_mirror
  v += __int_as_float(__builtin_amdgcn_ds_swizzle(__float_as_int(v), 0x401F));                    // xor 16
  float a = __int_as_float(__builtin_amdgcn_readlane(__float_as_int(v), 0));
  float b = __int_as_float(__builtin_amdgcn_readlane(__float_as_int(v), 32));
  return a + b;
}

__global__ void __launch_bounds__(NTHR, 2) rnn_persistent(
    const float* __restrict__ input_,
    const float* __restrict__ ewih, const float* __restrict__ ewhh,
    const float* __restrict__ ebih, const float* __restrict__ ebhh,
    const float* __restrict__ dwih, const float* __restrict__ dwhh,
    const float* __restrict__ dbih, const float* __restrict__ dbhh,
    const float* __restrict__ h2ow, const float* __restrict__ h2ob,
    float* __restrict__ out, char* __restrict__ ws, int tdec, int R)
{
  __shared__ alignas(16) _Float16 h_lds[2 * H_DIM];   // double buffer (parity of t)
  __shared__ float hred[8];
  __shared__ float redm[8], reds[8];
  __shared__ int   sidx[8];
  __shared__ int   idx_sh;

  u64* logits = (u64*)ws;
  u64* idxp   = (u64*)(ws + 4096);
  u32* gex    = (u32*)(ws + 8192);                 // replica 0 base

  const int tid  = threadIdx.x;
  const int lane = tid & 63;
  const int wid  = tid >> 6;
  const int blk  = blockIdx.x;
  const int j    = blk * 8 + wid;                  // hidden unit owned by this wave
  const u32* gexr = gex + (size_t)(blk & (R - 1)) * RSTR;  // replica this block polls

  WRegs W;
  load_weights(W, j, lane, ewih, ewhh, ebih, ebhh);
  float brz0 = W.bi[0] + W.bh[0];
  float brz1 = W.bi[1] + W.bh[1];

  float hold = 0.f;   // exact fp32 carry of h_j

  // ---------------- encoder ----------------
  // iter t: consume h(t) [tag t, slot t&3] from own replica; produce h(t+1)
  // into ALL replicas via ONE coalesced store instruction by wave 0 (8 x 32B
  // packets). memset gives {tag0,0.0f16} = valid h(0)=0 in every replica.
  // Poll protocol: CHECK-THEN-BACKOFF — the straggler block (which gates the
  // global step) detects in ~1 RT; waiting blocks sleep ~853ns then spin.
  for (u32 t = 0; t < L_SEQ; ++t) {
    _Float16* lbuf = h_lds + (t & 1) * H_DIM;
    const float* xr = input_ + (size_t)t * I_DIM + lane * 8;
    f4 xa = *(const f4*)xr;                  // issue early; L2-resident, drains
    f4 xb = *(const f4*)(xr + 4);            // under the try's LLC RT

    stage4(lbuf, gexr + (t & (BUFS - 1)) * H_DIM + tid * 4, t & 0xffffu, tid);

    // x-projection (post-detect; overlaps other waves' staging, pre-barrier)
    h2 xv[4] = { h2{(_Float16)xa[0], (_Float16)xa[1]}, h2{(_Float16)xa[2], (_Float16)xa[3]},
                 h2{(_Float16)xb[0], (_Float16)xb[1]}, h2{(_Float16)xb[2], (_Float16)xb[3]} };
    float ar = 0.f, az = 0.f, anx = 0.f, anh = 0.f;
#pragma unroll
    for (int q = 0; q < 4; ++q) {
      ar  = fdot2_(W.w[0][0][q], xv[q], ar);
      az  = fdot2_(W.w[1][0][q], xv[q], az);
      anx = fdot2_(W.w[2][0][q], xv[q], anx);
    }
    __syncthreads();   // stage4 LDS writes visible to all waves' dot_h reads

    dot_h(W, lbuf, lane, ar, az, anh);
    ar  = wave_sum(ar);
    az  = wave_sum(az);
    anx = wave_sum(anx);
    anh = wave_sum(anh);

    float r = fast_sigmoid(ar + brz0);
    float z = fast_sigmoid(az + brz1);
    float n = fast_tanh(anx + W.bi[2] + r * (anh + W.bh[2]));
    hold = (1.f - z) * n + z * hold;

    // coalesced multicast: lane 8k+i of wave 0 stores word i of replica k
    if (lane == 0) hred[wid] = hold;
    __syncthreads();
    if (wid == 0) {
      const u32 tg = (t + 1) & 0xffffu;
      const u32 sl = (t + 1) & (BUFS - 1);
      const int rep = lane >> 3, wi = lane & 7;
      u32 pk = packh(tg, hred[wi]);
      if (rep < R)
        ASTORE32((u32*)gex + (size_t)rep * RSTR + sl * H_DIM + blk * 8 + wi, pk);
    }
  }

  // ---------------- decoder ----------------
  load_weights(W, j, lane, dwih, dwhh, dbih, dbhh);
  brz0 = W.bi[0] + W.bh[0];
  brz1 = W.bi[1] + W.bh[1];
  __syncthreads();

  for (int d = 0; d < tdec; ++d) {
    const u32 t = L_SEQ + (u32)d;
    _Float16* lbuf = h_lds + (t & 1) * H_DIM;

    if (tid == 0) {
      int ix = -1;
      if (d > 0) {                          // poll one-hot index {tag d}
        u64 pk = ALOAD64(idxp);
        while (tag64(pk) != (u32)d) { __builtin_amdgcn_s_sleep(1); pk = ALOAD64(idxp); }
        ix = (int)(u32)pk;
      }
      idx_sh = ix;
    }
    stage4(lbuf, gexr + (t & (BUFS - 1)) * H_DIM + tid * 4, t & 0xffffu, tid);
    __syncthreads();
    const int idx = idx_sh;

    float ar = 0.f, az = 0.f, anx = 0.f, anh = 0.f;
    if (idx >= 0 && lane == (idx >> 3)) {
      const int qq = (idx & 7) >> 1;
      const int pp = idx & 1;
#pragma unroll
      for (int q = 0; q < 4; ++q) if (q == qq) {
        ar  += pp ? (float)W.w[0][0][q][1] : (float)W.w[0][0][q][0];
        az  += pp ? (float)W.w[1][0][q][1] : (float)W.w[1][0][q][0];
        anx += pp ? (float)W.w[2][0][q][1] : (float)W.w[2][0][q][0];
      }
    }
    dot_h(W, lbuf, lane, ar, az, anh);
    ar  = wave_sum(ar);
    az  = wave_sum(az);
    anx = wave_sum(anx);
    anh = wave_sum(anh);

    float r = fast_sigmoid(ar + brz0);
    float z = fast_sigmoid(az + brz1);
    float n = fast_tanh(anx + W.bi[2] + r * (anh + W.bh[2]));
    hold = (1.f - z) * n + z * hold;

    if (lane == 0) hred[wid] = hold;
    __syncthreads();
    if (wid == 0) {
      const u32 tg = (t + 1) & 0xffffu;
      const u32 sl = (t + 1) & (BUFS - 1);
      const int rep = lane >> 3, wi = lane & 7;
      u32 pk = packh(tg, hred[wi]);
      if (rep < R)
        ASTORE32((u32*)gex + (size_t)rep * RSTR + sl * H_DIM + blk * 8 + wi, pk);
    }

    // ---- logits: rows 2*blk, 2*blk+1; consume h(t+1) from own replica ----
    {
      const int row = 2 * blk + (tid >> 8);
      const int kk  = (tid & 255) * 8;
      const float* wrow = h2ow + (size_t)row * H_DIM + kk;
      f4 wa = *(const f4*)wrow, wb = *(const f4*)(wrow + 4);
      const u32* hp = gexr + ((t + 1) & (BUFS - 1)) * H_DIM + kk;
      const u32 htag = (t + 1) & 0xffffu;
      u32 g0, g1, g2, g3, g4, g5, g6, g7;
      poll_bk(hp,     htag, g0, g1, g2, g3);
      poll_bk(hp + 4, htag, g4, g5, g6, g7);
      float s = wa[0]*f16bits_to_f32(g0) + wa[1]*f16bits_to_f32(g1)
              + wa[2]*f16bits_to_f32(g2) + wa[3]*f16bits_to_f32(g3)
              + wb[0]*f16bits_to_f32(g4) + wb[1]*f16bits_to_f32(g5)
              + wb[2]*f16bits_to_f32(g6) + wb[3]*f16bits_to_f32(g7);
      s = wave_sum(s);
      if (lane == 0) redm[wid] = s;
      __syncthreads();
      if (tid == 0)
        ASTORE64(&logits[2 * blk],
                 pack64((u32)(d + 1), redm[0] + redm[1] + redm[2] + redm[3] + h2ob[2 * blk]));
      if (tid == 256)
        ASTORE64(&logits[2 * blk + 1],
                 pack64((u32)(d + 1), redm[4] + redm[5] + redm[6] + redm[7] + h2ob[2 * blk + 1]));
    }
    __syncthreads();

    // ---- log-softmax + argmax on block 0 (consumes tagged logits) ----
    if (blk == 0) {
      u64 pk = ALOAD64(&logits[tid]);
      while (tag64(pk) != (u32)(d + 1)) { __builtin_amdgcn_s_sleep(1); pk = ALOAD64(&logits[tid]); }
      float v = val64(pk);
      float m = v; int mi = tid;
#pragma unroll
      for (int off = 32; off > 0; off >>= 1) {
        float om = __shfl_xor(m, off, 64);
        int   oi = __shfl_xor(mi, off, 64);
        if (om > m || (om == m && oi < mi)) { m = om; mi = oi; }
      }
      if (lane == 0) { redm[wid] = m; sidx[wid] = mi; }
      __syncthreads();
      float M = redm[0]; int MI = sidx[0];
#pragma unroll
      for (int w2 = 1; w2 < 8; ++w2)
        if (redm[w2] > M || (redm[w2] == M && sidx[w2] < MI)) { M = redm[w2]; MI = sidx[w2]; }
      float ss = __expf(v - M);
#pragma unroll
      for (int off = 32; off > 0; off >>= 1) ss += __shfl_xor(ss, off, 64);
      if (lane == 0) reds[wid] = ss;
      __syncthreads();
      float S = reds[0] + reds[1] + reds[2] + reds[3]
              + reds[4] + reds[5] + reds[6] + reds[7];
      out[(size_t)d * O_DIM + tid] = v - M - __logf(S);
      if (tid == 0)
        ASTORE64(idxp, pack64((u32)(d + 1), (u32)MI));
    }
    __syncthreads();   // LDS reuse guard (decoder only; negligible at 30 steps)
  }
}

extern "C" void kernel_launch(void* const* d_in, const int* in_sizes, int n_in,
                              void* d_out, int out_size, void* d_ws, size_t ws_size,
                              hipStream_t stream) {
  const float* input_ = (const float*)d_in[0];
  const float* ewih   = (const float*)d_in[1];
  const float* ewhh   = (const float*)d_in[2];
  const float* ebih   = (const float*)d_in[3];
  const float* ebhh   = (const float*)d_in[4];
  const float* dwih   = (const float*)d_in[5];
  const float* dwhh   = (const float*)d_in[6];
  const float* dbih   = (const float*)d_in[7];
  const float* dbhh   = (const float*)d_in[8];
  const float* h2ow   = (const float*)d_in[9];
  const float* h2ob   = (const float*)d_in[10];
  float* out = (float*)d_out;
  char*  ws  = (char*)d_ws;
  int tdec = out_size / O_DIM;   // 30

  // replica count from actual workspace size (R=1 degrades gracefully)
  int R = 1;
  if (ws_size >= 8192 + 32768) {
    size_t maxr = (ws_size - 8192) / 32768;
    while (R * 2 <= (int)(maxr < 8 ? maxr : 8)) R *= 2;
  }
  size_t zbytes = 8192 + (size_t)R * 32768;

  // zero logits+idx+replicas (tag0 == valid h(0)=0 in every replica)
  hipMemsetAsync(d_ws, 0, zbytes, stream);

  void* args[] = { (void*)&input_, (void*)&ewih, (void*)&ewhh, (void*)&ebih, (void*)&ebhh,
                   (void*)&dwih, (void*)&dwhh, (void*)&dbih, (void*)&dbhh,
                   (void*)&h2ow, (void*)&h2ob, (void*)&out, (void*)&ws, (void*)&tdec,
                   (void*)&R };
  hipLaunchCooperativeKernel((void*)rnn_persistent, dim3(NBLK), dim3(NTHR),
                             args, 0, stream);
}

// Round 8
// 8042.681 us; speedup vs baseline: 1.6579x; 1.6009x over previous
//
#include <hip/hip_runtime.h>

#define L_SEQ 4096
#define I_DIM 512
#define H_DIM 2048
#define O_DIM 512
#define NBLK  256
#define NTHR  512
#define BUFS  4          // >=3 keeps tag-flow reuse skew-safe without barriers
#define RSTR (BUFS * H_DIM)   // u32 stride between mailbox replicas (32 KB)

// ws layout: [0:4K) logits u64[512] | [4K:4K+64) idx | [8K:...) replicas R x 32KB

typedef _Float16 h2 __attribute__((ext_vector_type(2)));
typedef float    f4 __attribute__((ext_vector_type(4)));
typedef unsigned int       u32;
typedef unsigned long long u64;
typedef u32 u32x4 __attribute__((ext_vector_type(4)));

struct __attribute__((aligned(16))) H4 { h2 v[4]; };

#define ALOAD64(p)     __hip_atomic_load((p), __ATOMIC_RELAXED, __HIP_MEMORY_SCOPE_AGENT)
#define ASTORE64(p, v) __hip_atomic_store((p), (v), __ATOMIC_RELAXED, __HIP_MEMORY_SCOPE_AGENT)
#define ALOAD32(p)     __hip_atomic_load((p), __ATOMIC_RELAXED, __HIP_MEMORY_SCOPE_AGENT)
#define ASTORE32(p, v) __hip_atomic_store((p), (v), __ATOMIC_RELAXED, __HIP_MEMORY_SCOPE_AGENT)

// Tagged poll of one 16B granule — SINGLE dwordx4 per check round (1 LLC
// transaction vs the old dual-generation scheme's 8 dword loads). Same 16
// bytes, same per-dword tags, so a read landing mid-publish (some dwords old
// generation) is still detected: all 4 tags must match. The load+drain live
// in ONE asm block (no in-flight registers escape — r6's hazard class).
// Wave-uniform exit via __all; s_sleep(1) between rounds. Post-sleep nearly
// all polls resolve in one round (r4 evidence), so the lost RT/2 pipelining
// quantum costs ~nothing while the grid-wide poll microburst shrinks ~8x.
__device__ __forceinline__ void poll_granule(const u32* p, u32 tag,
                                             u32& r0, u32& r1, u32& r2, u32& r3) {
  for (;;) {
    u32x4 A;
    asm volatile(
      "global_load_dwordx4 %[A], %[ptr], off sc0 sc1\n\t"
      "s_waitcnt vmcnt(0)"
      : [A]"=v"(A) : [ptr]"v"(p) : "memory");
    u32 bad = ((A[0] >> 16) ^ tag) | ((A[1] >> 16) ^ tag)
            | ((A[2] >> 16) ^ tag) | ((A[3] >> 16) ^ tag);
    if (__all(bad == 0)) { r0 = A[0]; r1 = A[1]; r2 = A[2]; r3 = A[3]; return; }
    __builtin_amdgcn_s_sleep(1);
  }
}

__device__ __forceinline__ float fdot2_(h2 a, h2 b, float c) {
#if __has_builtin(__builtin_amdgcn_fdot2)
  return __builtin_amdgcn_fdot2(a, b, c, false);
#else
  return c + (float)a[0] * (float)b[0] + (float)a[1] * (float)b[1];
#endif
}
__device__ __forceinline__ float fast_sigmoid(float x) {
  return __builtin_amdgcn_rcpf(1.f + __expf(-x));
}
__device__ __forceinline__ float fast_tanh(float x) {
  float xc = fminf(fmaxf(x, -15.f), 15.f);
  float e2 = __expf(2.f * xc);
  return (e2 - 1.f) * __builtin_amdgcn_rcpf(e2 + 1.f);
}

__device__ __forceinline__ u32 packh(u32 tag, float v) {
  union { _Float16 h; unsigned short u; } c; c.h = (_Float16)v;
  return (tag << 16) | (u32)c.u;
}
__device__ __forceinline__ float f16bits_to_f32(u32 w) {
  union { unsigned short u; _Float16 h; } c; c.u = (unsigned short)(w & 0xffff);
  return (float)c.h;
}
__device__ __forceinline__ u64 pack64(u32 tag, float v) {
  union { float f; u32 u; } c; c.f = v;
  return ((u64)tag << 32) | c.u;
}
__device__ __forceinline__ float val64(u64 pk) {
  union { u32 u; float f; } c; c.u = (u32)pk; return c.f;
}
__device__ __forceinline__ u32 tag64(u64 pk) { return (u32)(pk >> 32); }

struct WRegs {
  h2 w[3][5][4];     // [gate r/z/n][k-seg 0..4][pair]  seg0 = W_ih, seg1..4 = W_hh
  float bi[3], bh[3];
};

__device__ __forceinline__ void load_weights(WRegs& W, int j, int lane,
    const float* __restrict__ w_ih, const float* __restrict__ w_hh,
    const float* __restrict__ b_ih, const float* __restrict__ b_hh) {
#pragma unroll
  for (int g = 0; g < 3; ++g) {
    const float* rih = w_ih + ((size_t)g * H_DIM + j) * I_DIM + lane * 8;
#pragma unroll
    for (int hh = 0; hh < 2; ++hh) {
      f4 a = *(const f4*)(rih + 4 * hh);
      W.w[g][0][2*hh+0] = h2{(_Float16)a[0], (_Float16)a[1]};
      W.w[g][0][2*hh+1] = h2{(_Float16)a[2], (_Float16)a[3]};
    }
    const float* rhh = w_hh + ((size_t)g * H_DIM + j) * H_DIM + lane * 8;
#pragma unroll
    for (int s = 1; s < 5; ++s) {
#pragma unroll
      for (int hh = 0; hh < 2; ++hh) {
        f4 a = *(const f4*)(rhh + (s - 1) * 512 + 4 * hh);
        W.w[g][s][2*hh+0] = h2{(_Float16)a[0], (_Float16)a[1]};
        W.w[g][s][2*hh+1] = h2{(_Float16)a[2], (_Float16)a[3]};
      }
    }
    W.bi[g] = b_ih[g * H_DIM + j];
    W.bh[g] = b_hh[g * H_DIM + j];
  }
}

// Tag-synchronized h staging: poll own 16B granule, drop f16 payloads to LDS.
__device__ __forceinline__ void stage4(_Float16* lbuf, const u32* p, u32 tag, int tid) {
  u32 v0, v1, v2, v3;
  poll_granule(p, tag, v0, v1, v2, v3);
  u64 pk = (u64)((v0 & 0xffffu) | (v1 << 16))
         | ((u64)((v2 & 0xffffu) | (v3 << 16)) << 32);
  *(u64*)(lbuf + tid * 4) = pk;
}

__device__ __forceinline__ void dot_h(const WRegs& W, const _Float16* lbuf, int lane,
                                      float& ar, float& az, float& anh) {
#pragma unroll
  for (int s = 1; s < 5; ++s) {
    H4 hh = *(const H4*)(lbuf + (s - 1) * 512 + lane * 8);
#pragma unroll
    for (int q = 0; q < 4; ++q) {
      ar  = fdot2_(W.w[0][s][q], hh.v[q], ar);
      az  = fdot2_(W.w[1][s][q], hh.v[q], az);
      anh = fdot2_(W.w[2][s][q], hh.v[q], anh);
    }
  }
}

// Wave-64 sum with a short chain: 4 DPP VALU adds + one ds_swizzle (xor16)
// + 2 readlanes. Result is wave-uniform.
__device__ __forceinline__ float wave_sum(float v) {
  v += __int_as_float(__builtin_amdgcn_update_dpp(0, __float_as_int(v), 0xB1, 0xf, 0xf, false));  // quad_perm [1,0,3,2]
  v += __int_as_float(__builtin_amdgcn_update_dpp(0, __float_as_int(v), 0x4E, 0xf, 0xf, false));  // quad_perm [2,3,0,1]
  v += __int_as_float(__builtin_amdgcn_update_dpp(0, __float_as_int(v), 0x141, 0xf, 0xf, false)); // row_half_mirror
  v += __int_as_float(__builtin_amdgcn_update_dpp(0, __float_as_int(v), 0x140, 0xf, 0xf, false)); // row_mirror
  v += __int_as_float(__builtin_amdgcn_ds_swizzle(__float_as_int(v), 0x401F));                    // xor 16
  float a = __int_as_float(__builtin_amdgcn_readlane(__float_as_int(v), 0));
  float b = __int_as_float(__builtin_amdgcn_readlane(__float_as_int(v), 32));
  return a + b;
}

__global__ void __launch_bounds__(NTHR, 2) rnn_persistent(
    const float* __restrict__ input_,
    const float* __restrict__ ewih, const float* __restrict__ ewhh,
    const float* __restrict__ ebih, const float* __restrict__ ebhh,
    const float* __restrict__ dwih, const float* __restrict__ dwhh,
    const float* __restrict__ dbih, const float* __restrict__ dbhh,
    const float* __restrict__ h2ow, const float* __restrict__ h2ob,
    float* __restrict__ out, char* __restrict__ ws, int tdec, int R)
{
  __shared__ alignas(16) _Float16 h_lds[2 * H_DIM];   // double buffer (parity of t)
  __shared__ float hred[8];
  __shared__ float redm[8], reds[8];
  __shared__ int   sidx[8];
  __shared__ int   idx_sh;

  u64* logits = (u64*)ws;
  u64* idxp   = (u64*)(ws + 4096);
  u32* gex    = (u32*)(ws + 8192);                 // replica 0 base

  const int tid  = threadIdx.x;
  const int lane = tid & 63;
  const int wid  = tid >> 6;
  const int blk  = blockIdx.x;
  const int j    = blk * 8 + wid;                  // hidden unit owned by this wave
  const u32* gexr = gex + (size_t)(blk & (R - 1)) * RSTR;  // replica this block polls

  WRegs W;
  load_weights(W, j, lane, ewih, ewhh, ebih, ebhh);
  float brz0 = W.bi[0] + W.bh[0];
  float brz1 = W.bi[1] + W.bh[1];

  float hold = 0.f;   // exact fp32 carry of h_j

  // ---------------- encoder ----------------
  // iter t: consume h(t) [tag t, slot t&3] from own replica; produce h(t+1)
  // into ALL replicas via ONE coalesced store instruction by wave 0 (8 x 32B
  // packets). memset gives {tag0,0.0f16} = valid h(0)=0 in every replica.
  // Sleep-first poll protocol (r3/r6 lesson): the ~853ns backoff displaces
  // consumer reads out of the publish window; then ONE dwordx4 check usually
  // suffices. x loads issued at loop top; converted/dotted post-detect.
  for (u32 t = 0; t < L_SEQ; ++t) {
    _Float16* lbuf = h_lds + (t & 1) * H_DIM;
    const float* xr = input_ + (size_t)t * I_DIM + lane * 8;
    f4 xa = *(const f4*)xr;                  // issue early; consume post-detect
    f4 xb = *(const f4*)(xr + 4);

    if (t) __builtin_amdgcn_s_sleep(32);   // ~2048cy backoff: skip publish window
    stage4(lbuf, gexr + (t & (BUFS - 1)) * H_DIM + tid * 4, t & 0xffffu, tid);

    // x-projection (post-detect; overlaps other waves' staging, pre-barrier)
    h2 xv[4] = { h2{(_Float16)xa[0], (_Float16)xa[1]}, h2{(_Float16)xa[2], (_Float16)xa[3]},
                 h2{(_Float16)xb[0], (_Float16)xb[1]}, h2{(_Float16)xb[2], (_Float16)xb[3]} };
    float ar = 0.f, az = 0.f, anx = 0.f, anh = 0.f;
#pragma unroll
    for (int q = 0; q < 4; ++q) {
      ar  = fdot2_(W.w[0][0][q], xv[q], ar);
      az  = fdot2_(W.w[1][0][q], xv[q], az);
      anx = fdot2_(W.w[2][0][q], xv[q], anx);
    }
    __syncthreads();   // stage4 LDS writes visible to all waves' dot_h reads

    dot_h(W, lbuf, lane, ar, az, anh);
    ar  = wave_sum(ar);
    az  = wave_sum(az);
    anx = wave_sum(anx);
    anh = wave_sum(anh);

    float r = fast_sigmoid(ar + brz0);
    float z = fast_sigmoid(az + brz1);
    float n = fast_tanh(anx + W.bi[2] + r * (anh + W.bh[2]));
    hold = (1.f - z) * n + z * hold;

    // coalesced multicast: lane 8k+i of wave 0 stores word i of replica k
    if (lane == 0) hred[wid] = hold;
    __syncthreads();
    if (wid == 0) {
      const u32 tg = (t + 1) & 0xffffu;
      const u32 sl = (t + 1) & (BUFS - 1);
      const int rep = lane >> 3, wi = lane & 7;
      u32 pk = packh(tg, hred[wi]);
      if (rep < R)
        ASTORE32((u32*)gex + (size_t)rep * RSTR + sl * H_DIM + blk * 8 + wi, pk);
    }
  }

  // ---------------- decoder ----------------
  load_weights(W, j, lane, dwih, dwhh, dbih, dbhh);
  brz0 = W.bi[0] + W.bh[0];
  brz1 = W.bi[1] + W.bh[1];
  __syncthreads();

  for (int d = 0; d < tdec; ++d) {
    const u32 t = L_SEQ + (u32)d;
    _Float16* lbuf = h_lds + (t & 1) * H_DIM;

    if (tid == 0) {
      int ix = -1;
      if (d > 0) {                          // poll one-hot index {tag d}
        u64 pk = ALOAD64(idxp);
        while (tag64(pk) != (u32)d) { __builtin_amdgcn_s_sleep(1); pk = ALOAD64(idxp); }
        ix = (int)(u32)pk;
      }
      idx_sh = ix;
    }
    stage4(lbuf, gexr + (t & (BUFS - 1)) * H_DIM + tid * 4, t & 0xffffu, tid);
    __syncthreads();
    const int idx = idx_sh;

    float ar = 0.f, az = 0.f, anx = 0.f, anh = 0.f;
    if (idx >= 0 && lane == (idx >> 3)) {
      const int qq = (idx & 7) >> 1;
      const int pp = idx & 1;
#pragma unroll
      for (int q = 0; q < 4; ++q) if (q == qq) {
        ar  += pp ? (float)W.w[0][0][q][1] : (float)W.w[0][0][q][0];
        az  += pp ? (float)W.w[1][0][q][1] : (float)W.w[1][0][q][0];
        anx += pp ? (float)W.w[2][0][q][1] : (float)W.w[2][0][q][0];
      }
    }
    dot_h(W, lbuf, lane, ar, az, anh);
    ar  = wave_sum(ar);
    az  = wave_sum(az);
    anx = wave_sum(anx);
    anh = wave_sum(anh);

    float r = fast_sigmoid(ar + brz0);
    float z = fast_sigmoid(az + brz1);
    float n = fast_tanh(anx + W.bi[2] + r * (anh + W.bh[2]));
    hold = (1.f - z) * n + z * hold;

    if (lane == 0) hred[wid] = hold;
    __syncthreads();
    if (wid == 0) {
      const u32 tg = (t + 1) & 0xffffu;
      const u32 sl = (t + 1) & (BUFS - 1);
      const int rep = lane >> 3, wi = lane & 7;
      u32 pk = packh(tg, hred[wi]);
      if (rep < R)
        ASTORE32((u32*)gex + (size_t)rep * RSTR + sl * H_DIM + blk * 8 + wi, pk);
    }

    // ---- logits: rows 2*blk, 2*blk+1; consume h(t+1) from own replica ----
    {
      const int row = 2 * blk + (tid >> 8);
      const int kk  = (tid & 255) * 8;
      const float* wrow = h2ow + (size_t)row * H_DIM + kk;
      f4 wa = *(const f4*)wrow, wb = *(const f4*)(wrow + 4);
      const u32* hp = gexr + ((t + 1) & (BUFS - 1)) * H_DIM + kk;
      const u32 htag = (t + 1) & 0xffffu;
      u32 g0, g1, g2, g3, g4, g5, g6, g7;
      poll_granule(hp,     htag, g0, g1, g2, g3);
      poll_granule(hp + 4, htag, g4, g5, g6, g7);
      float s = wa[0]*f16bits_to_f32(g0) + wa[1]*f16bits_to_f32(g1)
              + wa[2]*f16bits_to_f32(g2) + wa[3]*f16bits_to_f32(g3)
              + wb[0]*f16bits_to_f32(g4) + wb[1]*f16bits_to_f32(g5)
              + wb[2]*f16bits_to_f32(g6) + wb[3]*f16bits_to_f32(g7);
      s = wave_sum(s);
      if (lane == 0) redm[wid] = s;
      __syncthreads();
      if (tid == 0)
        ASTORE64(&logits[2 * blk],
                 pack64((u32)(d + 1), redm[0] + redm[1] + redm[2] + redm[3] + h2ob[2 * blk]));
      if (tid == 256)
        ASTORE64(&logits[2 * blk + 1],
                 pack64((u32)(d + 1), redm[4] + redm[5] + redm[6] + redm[7] + h2ob[2 * blk + 1]));
    }
    __syncthreads();

    // ---- log-softmax + argmax on block 0 (consumes tagged logits) ----
    if (blk == 0) {
      u64 pk = ALOAD64(&logits[tid]);
      while (tag64(pk) != (u32)(d + 1)) { __builtin_amdgcn_s_sleep(1); pk = ALOAD64(&logits[tid]); }
      float v = val64(pk);
      float m = v; int mi = tid;
#pragma unroll
      for (int off = 32; off > 0; off >>= 1) {
        float om = __shfl_xor(m, off, 64);
        int   oi = __shfl_xor(mi, off, 64);
        if (om > m || (om == m && oi < mi)) { m = om; mi = oi; }
      }
      if (lane == 0) { redm[wid] = m; sidx[wid] = mi; }
      __syncthreads();
      float M = redm[0]; int MI = sidx[0];
#pragma unroll
      for (int w2 = 1; w2 < 8; ++w2)
        if (redm[w2] > M || (redm[w2] == M && sidx[w2] < MI)) { M = redm[w2]; MI = sidx[w2]; }
      float ss = __expf(v - M);
#pragma unroll
      for (int off = 32; off > 0; off >>= 1) ss += __shfl_xor(ss, off, 64);
      if (lane == 0) reds[wid] = ss;
      __syncthreads();
      float S = reds[0] + reds[1] + reds[2] + reds[3]
              + reds[4] + reds[5] + reds[6] + reds[7];
      out[(size_t)d * O_DIM + tid] = v - M - __logf(S);
      if (tid == 0)
        ASTORE64(idxp, pack64((u32)(d + 1), (u32)MI));
    }
    __syncthreads();   // LDS reuse guard (decoder only; negligible at 30 steps)
  }
}

extern "C" void kernel_launch(void* const* d_in, const int* in_sizes, int n_in,
                              void* d_out, int out_size, void* d_ws, size_t ws_size,
                              hipStream_t stream) {
  const float* input_ = (const float*)d_in[0];
  const float* ewih   = (const float*)d_in[1];
  const float* ewhh   = (const float*)d_in[2];
  const float* ebih   = (const float*)d_in[3];
  const float* ebhh   = (const float*)d_in[4];
  const float* dwih   = (const float*)d_in[5];
  const float* dwhh   = (const float*)d_in[6];
  const float* dbih   = (const float*)d_in[7];
  const float* dbhh   = (const float*)d_in[8];
  const float* h2ow   = (const float*)d_in[9];
  const float* h2ob   = (const float*)d_in[10];
  float* out = (float*)d_out;
  char*  ws  = (char*)d_ws;
  int tdec = out_size / O_DIM;   // 30

  // replica count from actual workspace size (R=1 degrades gracefully)
  int R = 1;
  if (ws_size >= 8192 + 32768) {
    size_t maxr = (ws_size - 8192) / 32768;
    while (R * 2 <= (int)(maxr < 8 ? maxr : 8)) R *= 2;
  }
  size_t zbytes = 8192 + (size_t)R * 32768;

  // zero logits+idx+replicas (tag0 == valid h(0)=0 in every replica)
  hipMemsetAsync(d_ws, 0, zbytes, stream);

  void* args[] = { (void*)&input_, (void*)&ewih, (void*)&ewhh, (void*)&ebih, (void*)&ebhh,
                   (void*)&dwih, (void*)&dwhh, (void*)&dbih, (void*)&dbhh,
                   (void*)&h2ow, (void*)&h2ob, (void*)&out, (void*)&ws, (void*)&tdec,
                   (void*)&R };
  hipLaunchCooperativeKernel((void*)rnn_persistent, dim3(NBLK), dim3(NTHR),
                             args, 0, stream);
}

// Round 9
// 6672.156 us; speedup vs baseline: 1.9984x; 1.2054x over previous
//
#include <hip/hip_runtime.h>

#define L_SEQ 4096
#define I_DIM 512
#define H_DIM 2048
#define O_DIM 512
#define NBLK  256
#define NTHR  512
#define BUFS  4          // >=3 keeps tag-flow reuse skew-safe without barriers
#define RSTR (BUFS * H_DIM)   // u32 stride between mailbox replicas (32 KB)

// ws layout: [0:4K) logits u64[512] | [4K:4K+64) idx | [8K:...) replicas R x 32KB

typedef _Float16 h2 __attribute__((ext_vector_type(2)));
typedef float    f4 __attribute__((ext_vector_type(4)));
typedef unsigned int       u32;
typedef unsigned long long u64;
typedef u32 u32x4 __attribute__((ext_vector_type(4)));

struct __attribute__((aligned(16))) H4 { h2 v[4]; };

#define ALOAD64(p)     __hip_atomic_load((p), __ATOMIC_RELAXED, __HIP_MEMORY_SCOPE_AGENT)
#define ASTORE64(p, v) __hip_atomic_store((p), (v), __ATOMIC_RELAXED, __HIP_MEMORY_SCOPE_AGENT)
#define ALOAD32(p)     __hip_atomic_load((p), __ATOMIC_RELAXED, __HIP_MEMORY_SCOPE_AGENT)
#define ASTORE32(p, v) __hip_atomic_store((p), (v), __ATOMIC_RELAXED, __HIP_MEMORY_SCOPE_AGENT)

// Tagged poll of one 16B granule — SINGLE dwordx4 per check round (1 LLC
// transaction; r8 proved the fabric is op-limited: 8 dwords -> 1 dwordx4 was
// -29% total time with FETCH bytes unchanged). Per-dword tags, so a read
// landing mid-publish is detected (all 4 tags must match). Load+drain in one
// asm block; wave-uniform exit via __all; s_sleep(1) paces retry rounds.
__device__ __forceinline__ void poll_granule(const u32* p, u32 tag,
                                             u32& r0, u32& r1, u32& r2, u32& r3) {
  for (;;) {
    u32x4 A;
    asm volatile(
      "global_load_dwordx4 %[A], %[ptr], off sc0 sc1\n\t"
      "s_waitcnt vmcnt(0)"
      : [A]"=v"(A) : [ptr]"v"(p) : "memory");
    u32 bad = ((A[0] >> 16) ^ tag) | ((A[1] >> 16) ^ tag)
            | ((A[2] >> 16) ^ tag) | ((A[3] >> 16) ^ tag);
    if (__all(bad == 0)) { r0 = A[0]; r1 = A[1]; r2 = A[2]; r3 = A[3]; return; }
    __builtin_amdgcn_s_sleep(1);
  }
}

__device__ __forceinline__ float fdot2_(h2 a, h2 b, float c) {
#if __has_builtin(__builtin_amdgcn_fdot2)
  return __builtin_amdgcn_fdot2(a, b, c, false);
#else
  return c + (float)a[0] * (float)b[0] + (float)a[1] * (float)b[1];
#endif
}
__device__ __forceinline__ float fast_sigmoid(float x) {
  return __builtin_amdgcn_rcpf(1.f + __expf(-x));
}
__device__ __forceinline__ float fast_tanh(float x) {
  float xc = fminf(fmaxf(x, -15.f), 15.f);
  float e2 = __expf(2.f * xc);
  return (e2 - 1.f) * __builtin_amdgcn_rcpf(e2 + 1.f);
}

__device__ __forceinline__ u32 packh(u32 tag, float v) {
  union { _Float16 h; unsigned short u; } c; c.h = (_Float16)v;
  return (tag << 16) | (u32)c.u;
}
__device__ __forceinline__ float f16bits_to_f32(u32 w) {
  union { unsigned short u; _Float16 h; } c; c.u = (unsigned short)(w & 0xffff);
  return (float)c.h;
}
__device__ __forceinline__ u64 pack64(u32 tag, float v) {
  union { float f; u32 u; } c; c.f = v;
  return ((u64)tag << 32) | c.u;
}
__device__ __forceinline__ float val64(u64 pk) {
  union { u32 u; float f; } c; c.u = (u32)pk; return c.f;
}
__device__ __forceinline__ u32 tag64(u64 pk) { return (u32)(pk >> 32); }

struct WRegs {
  h2 w[3][5][4];     // [gate r/z/n][k-seg 0..4][pair]  seg0 = W_ih, seg1..4 = W_hh
  float bi[3], bh[3];
};

__device__ __forceinline__ void load_weights(WRegs& W, int j, int lane,
    const float* __restrict__ w_ih, const float* __restrict__ w_hh,
    const float* __restrict__ b_ih, const float* __restrict__ b_hh) {
#pragma unroll
  for (int g = 0; g < 3; ++g) {
    const float* rih = w_ih + ((size_t)g * H_DIM + j) * I_DIM + lane * 8;
#pragma unroll
    for (int hh = 0; hh < 2; ++hh) {
      f4 a = *(const f4*)(rih + 4 * hh);
      W.w[g][0][2*hh+0] = h2{(_Float16)a[0], (_Float16)a[1]};
      W.w[g][0][2*hh+1] = h2{(_Float16)a[2], (_Float16)a[3]};
    }
    const float* rhh = w_hh + ((size_t)g * H_DIM + j) * H_DIM + lane * 8;
#pragma unroll
    for (int s = 1; s < 5; ++s) {
#pragma unroll
      for (int hh = 0; hh < 2; ++hh) {
        f4 a = *(const f4*)(rhh + (s - 1) * 512 + 4 * hh);
        W.w[g][s][2*hh+0] = h2{(_Float16)a[0], (_Float16)a[1]};
        W.w[g][s][2*hh+1] = h2{(_Float16)a[2], (_Float16)a[3]};
      }
    }
    W.bi[g] = b_ih[g * H_DIM + j];
    W.bh[g] = b_hh[g * H_DIM + j];
  }
}

// Tag-synchronized h staging: poll own 16B granule, drop f16 payloads to LDS.
__device__ __forceinline__ void stage4(_Float16* lbuf, const u32* p, u32 tag, int tid) {
  u32 v0, v1, v2, v3;
  poll_granule(p, tag, v0, v1, v2, v3);
  u64 pk = (u64)((v0 & 0xffffu) | (v1 << 16))
         | ((u64)((v2 & 0xffffu) | (v3 << 16)) << 32);
  *(u64*)(lbuf + tid * 4) = pk;
}

__device__ __forceinline__ void dot_h(const WRegs& W, const _Float16* lbuf, int lane,
                                      float& ar, float& az, float& anh) {
#pragma unroll
  for (int s = 1; s < 5; ++s) {
    H4 hh = *(const H4*)(lbuf + (s - 1) * 512 + lane * 8);
#pragma unroll
    for (int q = 0; q < 4; ++q) {
      ar  = fdot2_(W.w[0][s][q], hh.v[q], ar);
      az  = fdot2_(W.w[1][s][q], hh.v[q], az);
      anh = fdot2_(W.w[2][s][q], hh.v[q], anh);
    }
  }
}

// Wave-64 sum with a short chain: 4 DPP VALU adds + one ds_swizzle (xor16)
// + 2 readlanes. Result is wave-uniform.
__device__ __forceinline__ float wave_sum(float v) {
  v += __int_as_float(__builtin_amdgcn_update_dpp(0, __float_as_int(v), 0xB1, 0xf, 0xf, false));  // quad_perm [1,0,3,2]
  v += __int_as_float(__builtin_amdgcn_update_dpp(0, __float_as_int(v), 0x4E, 0xf, 0xf, false));  // quad_perm [2,3,0,1]
  v += __int_as_float(__builtin_amdgcn_update_dpp(0, __float_as_int(v), 0x141, 0xf, 0xf, false)); // row_half_mirror
  v += __int_as_float(__builtin_amdgcn_update_dpp(0, __float_as_int(v), 0x140, 0xf, 0xf, false)); // row_mirror
  v += __int_as_float(__builtin_amdgcn_ds_swizzle(__float_as_int(v), 0x401F));                    // xor 16
  float a = __int_as_float(__builtin_amdgcn_readlane(__float_as_int(v), 0));
  float b = __int_as_float(__builtin_amdgcn_readlane(__float_as_int(v), 32));
  return a + b;
}

__global__ void __launch_bounds__(NTHR, 2) rnn_persistent(
    const float* __restrict__ input_,
    const float* __restrict__ ewih, const float* __restrict__ ewhh,
    const float* __restrict__ ebih, const float* __restrict__ ebhh,
    const float* __restrict__ dwih, const float* __restrict__ dwhh,
    const float* __restrict__ dbih, const float* __restrict__ dbhh,
    const float* __restrict__ h2ow, const float* __restrict__ h2ob,
    float* __restrict__ out, char* __restrict__ ws, int tdec, int R)
{
  __shared__ alignas(16) _Float16 h_lds[2 * H_DIM];   // double buffer (parity of t)
  __shared__ float hred[8];
  __shared__ float redm[8], reds[8];
  __shared__ int   sidx[8];
  __shared__ int   idx_sh;

  u64* logits = (u64*)ws;
  u64* idxp   = (u64*)(ws + 4096);
  u32* gex    = (u32*)(ws + 8192);                 // replica 0 base

  const int tid  = threadIdx.x;
  const int lane = tid & 63;
  const int wid  = tid >> 6;
  const int blk  = blockIdx.x;
  const int j    = blk * 8 + wid;                  // hidden unit owned by this wave
  const u32* gexr = gex + (size_t)(blk & (R - 1)) * RSTR;  // replica this block polls

  WRegs W;
  load_weights(W, j, lane, ewih, ewhh, ebih, ebhh);
  float brz0 = W.bi[0] + W.bh[0];
  float brz1 = W.bi[1] + W.bh[1];

  float hold = 0.f;   // exact fp32 carry of h_j

  // ---------------- encoder ----------------
  // iter t: consume h(t) [tag t, slot t&3] from own replica; produce h(t+1)
  // into ALL replicas via ONE coalesced store instruction by wave 0 (8 x 32B
  // packets). memset gives {tag0,0.0f16} = valid h(0)=0 in every replica.
  // Sleep-first poll protocol, TUNED: r8's timing model puts store visibility
  // at ~600ns post-publish; s_sleep(16) (~427ns) launches the poll so its LLC
  // sample lands just after visibility — first-round hit with ~400ns less
  // dead time than the previous s_sleep(32). Reads stay displaced out of the
  // publish window (r6 lesson); checks are 1 transaction each (r8 lesson).
  for (u32 t = 0; t < L_SEQ; ++t) {
    _Float16* lbuf = h_lds + (t & 1) * H_DIM;
    const float* xr = input_ + (size_t)t * I_DIM + lane * 8;
    f4 xa = *(const f4*)xr;                  // issue early; consume post-detect
    f4 xb = *(const f4*)(xr + 4);

    if (t) __builtin_amdgcn_s_sleep(16);   // ~1024cy: skip publish window only
    stage4(lbuf, gexr + (t & (BUFS - 1)) * H_DIM + tid * 4, t & 0xffffu, tid);

    // x-projection (post-detect; overlaps other waves' staging, pre-barrier)
    h2 xv[4] = { h2{(_Float16)xa[0], (_Float16)xa[1]}, h2{(_Float16)xa[2], (_Float16)xa[3]},
                 h2{(_Float16)xb[0], (_Float16)xb[1]}, h2{(_Float16)xb[2], (_Float16)xb[3]} };
    float ar = 0.f, az = 0.f, anx = 0.f, anh = 0.f;
#pragma unroll
    for (int q = 0; q < 4; ++q) {
      ar  = fdot2_(W.w[0][0][q], xv[q], ar);
      az  = fdot2_(W.w[1][0][q], xv[q], az);
      anx = fdot2_(W.w[2][0][q], xv[q], anx);
    }
    __syncthreads();   // stage4 LDS writes visible to all waves' dot_h reads

    dot_h(W, lbuf, lane, ar, az, anh);
    ar  = wave_sum(ar);
    az  = wave_sum(az);
    anx = wave_sum(anx);
    anh = wave_sum(anh);

    float r = fast_sigmoid(ar + brz0);
    float z = fast_sigmoid(az + brz1);
    float n = fast_tanh(anx + W.bi[2] + r * (anh + W.bh[2]));
    hold = (1.f - z) * n + z * hold;

    // coalesced multicast: lane 8k+i of wave 0 stores word i of replica k
    if (lane == 0) hred[wid] = hold;
    __syncthreads();
    if (wid == 0) {
      const u32 tg = (t + 1) & 0xffffu;
      const u32 sl = (t + 1) & (BUFS - 1);
      const int rep = lane >> 3, wi = lane & 7;
      u32 pk = packh(tg, hred[wi]);
      if (rep < R)
        ASTORE32((u32*)gex + (size_t)rep * RSTR + sl * H_DIM + blk * 8 + wi, pk);
    }
  }

  // ---------------- decoder ----------------
  load_weights(W, j, lane, dwih, dwhh, dbih, dbhh);
  brz0 = W.bi[0] + W.bh[0];
  brz1 = W.bi[1] + W.bh[1];
  __syncthreads();

  for (int d = 0; d < tdec; ++d) {
    const u32 t = L_SEQ + (u32)d;
    _Float16* lbuf = h_lds + (t & 1) * H_DIM;

    if (tid == 0) {
      int ix = -1;
      if (d > 0) {                          // poll one-hot index {tag d}
        u64 pk = ALOAD64(idxp);
        while (tag64(pk) != (u32)d) { __builtin_amdgcn_s_sleep(1); pk = ALOAD64(idxp); }
        ix = (int)(u32)pk;
      }
      idx_sh = ix;
    }
    stage4(lbuf, gexr + (t & (BUFS - 1)) * H_DIM + tid * 4, t & 0xffffu, tid);
    __syncthreads();
    const int idx = idx_sh;

    float ar = 0.f, az = 0.f, anx = 0.f, anh = 0.f;
    if (idx >= 0 && lane == (idx >> 3)) {
      const int qq = (idx & 7) >> 1;
      const int pp = idx & 1;
#pragma unroll
      for (int q = 0; q < 4; ++q) if (q == qq) {
        ar  += pp ? (float)W.w[0][0][q][1] : (float)W.w[0][0][q][0];
        az  += pp ? (float)W.w[1][0][q][1] : (float)W.w[1][0][q][0];
        anx += pp ? (float)W.w[2][0][q][1] : (float)W.w[2][0][q][0];
      }
    }
    dot_h(W, lbuf, lane, ar, az, anh);
    ar  = wave_sum(ar);
    az  = wave_sum(az);
    anx = wave_sum(anx);
    anh = wave_sum(anh);

    float r = fast_sigmoid(ar + brz0);
    float z = fast_sigmoid(az + brz1);
    float n = fast_tanh(anx + W.bi[2] + r * (anh + W.bh[2]));
    hold = (1.f - z) * n + z * hold;

    if (lane == 0) hred[wid] = hold;
    __syncthreads();
    if (wid == 0) {
      const u32 tg = (t + 1) & 0xffffu;
      const u32 sl = (t + 1) & (BUFS - 1);
      const int rep = lane >> 3, wi = lane & 7;
      u32 pk = packh(tg, hred[wi]);
      if (rep < R)
        ASTORE32((u32*)gex + (size_t)rep * RSTR + sl * H_DIM + blk * 8 + wi, pk);
    }

    // ---- logits: rows 2*blk, 2*blk+1; consume h(t+1) from own replica ----
    {
      const int row = 2 * blk + (tid >> 8);
      const int kk  = (tid & 255) * 8;
      const float* wrow = h2ow + (size_t)row * H_DIM + kk;
      f4 wa = *(const f4*)wrow, wb = *(const f4*)(wrow + 4);
      const u32* hp = gexr + ((t + 1) & (BUFS - 1)) * H_DIM + kk;
      const u32 htag = (t + 1) & 0xffffu;
      u32 g0, g1, g2, g3, g4, g5, g6, g7;
      poll_granule(hp,     htag, g0, g1, g2, g3);
      poll_granule(hp + 4, htag, g4, g5, g6, g7);
      float s = wa[0]*f16bits_to_f32(g0) + wa[1]*f16bits_to_f32(g1)
              + wa[2]*f16bits_to_f32(g2) + wa[3]*f16bits_to_f32(g3)
              + wb[0]*f16bits_to_f32(g4) + wb[1]*f16bits_to_f32(g5)
              + wb[2]*f16bits_to_f32(g6) + wb[3]*f16bits_to_f32(g7);
      s = wave_sum(s);
      if (lane == 0) redm[wid] = s;
      __syncthreads();
      if (tid == 0)
        ASTORE64(&logits[2 * blk],
                 pack64((u32)(d + 1), redm[0] + redm[1] + redm[2] + redm[3] + h2ob[2 * blk]));
      if (tid == 256)
        ASTORE64(&logits[2 * blk + 1],
                 pack64((u32)(d + 1), redm[4] + redm[5] + redm[6] + redm[7] + h2ob[2 * blk + 1]));
    }
    __syncthreads();

    // ---- log-softmax + argmax on block 0 (consumes tagged logits) ----
    if (blk == 0) {
      u64 pk = ALOAD64(&logits[tid]);
      while (tag64(pk) != (u32)(d + 1)) { __builtin_amdgcn_s_sleep(1); pk = ALOAD64(&logits[tid]); }
      float v = val64(pk);
      float m = v; int mi = tid;
#pragma unroll
      for (int off = 32; off > 0; off >>= 1) {
        float om = __shfl_xor(m, off, 64);
        int   oi = __shfl_xor(mi, off, 64);
        if (om > m || (om == m && oi < mi)) { m = om; mi = oi; }
      }
      if (lane == 0) { redm[wid] = m; sidx[wid] = mi; }
      __syncthreads();
      float M = redm[0]; int MI = sidx[0];
#pragma unroll
      for (int w2 = 1; w2 < 8; ++w2)
        if (redm[w2] > M || (redm[w2] == M && sidx[w2] < MI)) { M = redm[w2]; MI = sidx[w2]; }
      float ss = __expf(v - M);
#pragma unroll
      for (int off = 32; off > 0; off >>= 1) ss += __shfl_xor(ss, off, 64);
      if (lane == 0) reds[wid] = ss;
      __syncthreads();
      float S = reds[0] + reds[1] + reds[2] + reds[3]
              + reds[4] + reds[5] + reds[6] + reds[7];
      out[(size_t)d * O_DIM + tid] = v - M - __logf(S);
      if (tid == 0)
        ASTORE64(idxp, pack64((u32)(d + 1), (u32)MI));
    }
    __syncthreads();   // LDS reuse guard (decoder only; negligible at 30 steps)
  }
}

extern "C" void kernel_launch(void* const* d_in, const int* in_sizes, int n_in,
                              void* d_out, int out_size, void* d_ws, size_t ws_size,
                              hipStream_t stream) {
  const float* input_ = (const float*)d_in[0];
  const float* ewih   = (const float*)d_in[1];
  const float* ewhh   = (const float*)d_in[2];
  const float* ebih   = (const float*)d_in[3];
  const float* ebhh   = (const float*)d_in[4];
  const float* dwih   = (const float*)d_in[5];
  const float* dwhh   = (const float*)d_in[6];
  const float* dbih   = (const float*)d_in[7];
  const float* dbhh   = (const float*)d_in[8];
  const float* h2ow   = (const float*)d_in[9];
  const float* h2ob   = (const float*)d_in[10];
  float* out = (float*)d_out;
  char*  ws  = (char*)d_ws;
  int tdec = out_size / O_DIM;   // 30

  // replica count from actual workspace size (R=1 degrades gracefully)
  int R = 1;
  if (ws_size >= 8192 + 32768) {
    size_t maxr = (ws_size - 8192) / 32768;
    while (R * 2 <= (int)(maxr < 8 ? maxr : 8)) R *= 2;
  }
  size_t zbytes = 8192 + (size_t)R * 32768;

  // zero logits+idx+replicas (tag0 == valid h(0)=0 in every replica)
  hipMemsetAsync(d_ws, 0, zbytes, stream);

  void* args[] = { (void*)&input_, (void*)&ewih, (void*)&ewhh, (void*)&ebih, (void*)&ebhh,
                   (void*)&dwih, (void*)&dwhh, (void*)&dbih, (void*)&dbhh,
                   (void*)&h2ow, (void*)&h2ob, (void*)&out, (void*)&ws, (void*)&tdec,
                   (void*)&R };
  hipLaunchCooperativeKernel((void*)rnn_persistent, dim3(NBLK), dim3(NTHR),
                             args, 0, stream);
}